// Round 1
// baseline (729.268 us; speedup 1.0000x reference)
//
#include <hip/hip_runtime.h>

#define BATCH 16
#define CH    64
#define HW_PX 65536
#define NB2   256           // pass-2 blocks per batch (was 64): 4096 blocks -> 8 resident/CU
#define PX2   256
#define NT2   4
#define PARTIAL_STRIDE 4160 // 4096 cov partial + 64 channel sums

using bf16x8 = __attribute__((ext_vector_type(8))) short;   // 8 bf16 in 4 VGPRs
using f32x16 = __attribute__((ext_vector_type(16))) float;
using f32x4  = __attribute__((ext_vector_type(4))) float;

__device__ inline unsigned short bf16_rne(float f) {
    unsigned int u = __builtin_bit_cast(unsigned int, f);
    u += 0x7FFFu + ((u >> 16) & 1u);
    return (unsigned short)(u >> 16);
}
__device__ inline float bf16_f32(unsigned short s) {
    unsigned int u = ((unsigned int)s) << 16;
    return __builtin_bit_cast(float, u);
}
// XOR-swizzled index into a 64x64 (row,col) short array: 16B-chunk swizzle keeps
// ds_read_b128 at the 4-lane/bank floor for both row-fragment reads and staging writes.
__device__ inline int sw_idx(int row, int col) {
    return row * 64 + ((((col >> 3) ^ (row & 7)) << 3) | (col & 7));
}
__device__ inline bf16x8 ld_frag8(const short* m, int row, int o) {
    return *(const bf16x8*)&m[row * 64 + ((o ^ (row & 7)) << 3)];
}
// C += A*B for one 32x32 quadrant; A,B stored as hi/lo bf16 pairs (split-fp32).
// B is accessed via rows of B (valid because every B we pass is symmetric).
__device__ inline void mm_quad_hilo(f32x16& acc,
        const short* Ah, const short* Al,
        const short* Bh, const short* Bl,
        int ra, int rb, int lane) {
    #pragma unroll
    for (int kc = 0; kc < 4; ++kc) {
        int o = kc * 2 + (lane >> 5);
        bf16x8 ah = ld_frag8(Ah, ra, o);
        bf16x8 al = ld_frag8(Al, ra, o);
        bf16x8 bh = ld_frag8(Bh, rb, o);
        bf16x8 bl = ld_frag8(Bl, rb, o);
        acc = __builtin_amdgcn_mfma_f32_32x32x16_bf16(ah, bh, acc, 0, 0, 0);
        acc = __builtin_amdgcn_mfma_f32_32x32x16_bf16(ah, bl, acc, 0, 0, 0);
        acc = __builtin_amdgcn_mfma_f32_32x32x16_bf16(al, bh, acc, 0, 0, 0);
    }
}
// write quadrant back to LDS as hi/lo bf16: M = v*scale + diag*I
__device__ inline void wb_hilo(short* Mh, short* Ml, const f32x16& v,
                               int r, int cq, int lane, float scale, float diag) {
    #pragma unroll
    for (int reg = 0; reg < 16; ++reg) {
        int row = 32 * r + (reg & 3) + 8 * (reg >> 2) + 4 * (lane >> 5);
        int col = 32 * cq + (lane & 31);
        float f = v[reg] * scale + ((row == col) ? diag : 0.0f);
        unsigned short hi = bf16_rne(f);
        float lo = f - bf16_f32(hi);
        int idx = sw_idx(row, col);
        Mh[idx] = (short)hi;
        Ml[idx] = (short)bf16_rne(lo);
    }
}

// ---------------- Pass 1: per-batch Sum(x) and Sum(x x^T) partials ----------------
template<int NB1T>
__global__ __launch_bounds__(256) void pass1_cov(const float* __restrict__ x,
                                                 float* __restrict__ partial) {
    constexpr int PX1T = HW_PX / NB1T;   // pixels per block
    constexpr int NT1T = PX1T / 64;      // 64-pixel tiles per block
    const int blk = blockIdx.x;
    const int b = blk / NB1T;
    const int chunk = blk % NB1T;
    const size_t base = (size_t)b * HW_PX * CH + (size_t)chunk * PX1T * CH;
    const int t = threadIdx.x;
    const int lane = t & 63;
    const int wave = t >> 6;
    const int r = wave >> 1, cq = wave & 1;
    const int s_ch = t & 63;   // staging: this thread's channel
    const int s_og = t >> 6;   // staging: octet group

    __shared__ __align__(16) short xs[2][4096];  // double-buffered 64px x 64ch bf16, swizzled
    __shared__ float fsum[256];

    f32x16 acc;
    #pragma unroll
    for (int i = 0; i < 16; ++i) acc[i] = 0.0f;
    float csum = 0.0f;

    // stage tile 0
    {
        const size_t tb = base;
        #pragma unroll
        for (int p = 0; p < 2; ++p) {
            const int o = s_og + 4 * p;
            bf16x8 w;
            #pragma unroll
            for (int j = 0; j < 8; ++j) {
                float v = x[tb + (size_t)(o * 8 + j) * CH + s_ch];
                csum += v;
                w[j] = (short)bf16_rne(v);
            }
            *(bf16x8*)&xs[0][s_ch * 64 + ((o ^ (s_ch & 7)) << 3)] = w;
        }
    }
    __syncthreads();

    const int ra = 32 * r + (lane & 31);
    const int rb = 32 * cq + (lane & 31);

    for (int tile = 0; tile < NT1T; ++tile) {
        const int cur = tile & 1;
        if (tile + 1 < NT1T) {
            const size_t tb = base + (size_t)(tile + 1) * 64 * CH;
            const int nb = cur ^ 1;
            #pragma unroll
            for (int p = 0; p < 2; ++p) {
                const int o = s_og + 4 * p;
                bf16x8 w;
                #pragma unroll
                for (int j = 0; j < 8; ++j) {
                    float v = x[tb + (size_t)(o * 8 + j) * CH + s_ch];
                    csum += v;
                    w[j] = (short)bf16_rne(v);
                }
                *(bf16x8*)&xs[nb][s_ch * 64 + ((o ^ (s_ch & 7)) << 3)] = w;
            }
        }
        #pragma unroll
        for (int kc = 0; kc < 4; ++kc) {
            const int o = kc * 2 + (lane >> 5);
            bf16x8 af = *(const bf16x8*)&xs[cur][ra * 64 + ((o ^ (ra & 7)) << 3)];
            bf16x8 bg = *(const bf16x8*)&xs[cur][rb * 64 + ((o ^ (rb & 7)) << 3)];
            acc = __builtin_amdgcn_mfma_f32_32x32x16_bf16(af, bg, acc, 0, 0, 0);
        }
        __syncthreads();
    }

    float* myp = partial + (size_t)blk * PARTIAL_STRIDE;
    #pragma unroll
    for (int reg = 0; reg < 16; ++reg) {
        int row = 32 * r + (reg & 3) + 8 * (reg >> 2) + 4 * (lane >> 5);
        int col = 32 * cq + (lane & 31);
        myp[row * 64 + col] = acc[reg];
    }
    fsum[t] = csum;
    __syncthreads();
    if (t < 64) {
        myp[4096 + t] = fsum[t] + fsum[t + 64] + fsum[t + 128] + fsum[t + 192];
    }
}

// ------- Reduce partials -> cov, then coupled Newton-Schulz: Y->cov^1/2, Z->cov^-1/2 -------
template<int NB1T>
__global__ __launch_bounds__(256) void ns_sqrt(
        const float* __restrict__ partial,
        float* __restrict__ meanv,
        float* __restrict__ Ym, float* __restrict__ Zm) {
    const int b = blockIdx.x;
    const int t = threadIdx.x;
    const int lane = t & 63;
    const int wave = t >> 6;
    const int r = wave >> 1, cq = wave & 1;
    __shared__ __align__(16) short Yh[4096], Yl[4096], Zh[4096], Zl[4096], Ph[4096], Pl[4096];
    __shared__ float msh[64];
    __shared__ float csh;
    float* Cf = (float*)Ph;   // reuse P storage (16 KB) for the fp32 cov before iterations

    if (t < 64) {
        float s = 0.0f;
        for (int k = 0; k < NB1T; ++k)
            s += partial[(size_t)(b * NB1T + k) * PARTIAL_STRIDE + 4096 + t];
        float m = s / (float)HW_PX;
        msh[t] = m;
        meanv[b * 64 + t] = m;
    }
    __syncthreads();
    const float invn = 1.0f / (float)(HW_PX - 1);
    for (int e = t; e < 4096; e += 256) {
        float s = 0.0f;
        for (int k = 0; k < NB1T; ++k)
            s += partial[(size_t)(b * NB1T + k) * PARTIAL_STRIDE + e];
        int i = e >> 6, j = e & 63;
        Cf[e] = (s - (float)HW_PX * msh[i] * msh[j]) * invn;
    }
    __syncthreads();
    if (t == 0) {
        float tr = 0.0f;
        for (int i = 0; i < 64; ++i) tr += Cf[i * 64 + i];
        csh = 64.0f / tr;
    }
    __syncthreads();
    const float invc = csh;
    for (int e = t; e < 4096; e += 256) {
        int row = e >> 6, col = e & 63;
        float y = Cf[e] * invc;
        unsigned short hi = bf16_rne(y);
        float lo = y - bf16_f32(hi);
        int idx = sw_idx(row, col);
        Yh[idx] = (short)hi; Yl[idx] = (short)bf16_rne(lo);
        Zh[idx] = (row == col) ? (short)0x3F80 : (short)0;
        Zl[idx] = 0;
    }
    __syncthreads();

    const int ra = 32 * r + (lane & 31);
    const int rb = 32 * cq + (lane & 31);
    for (int it = 0; it < 5; ++it) {
        f32x16 tacc;
        #pragma unroll
        for (int i = 0; i < 16; ++i) tacc[i] = 0.0f;
        mm_quad_hilo(tacc, Zh, Zl, Yh, Yl, ra, rb, lane);      // T = Z*Y
        wb_hilo(Ph, Pl, tacc, r, cq, lane, -0.5f, 1.5f);       // P = 1.5I - 0.5T
        __syncthreads();
        f32x16 ya, za;
        #pragma unroll
        for (int i = 0; i < 16; ++i) { ya[i] = 0.0f; za[i] = 0.0f; }
        mm_quad_hilo(ya, Yh, Yl, Ph, Pl, ra, rb, lane);        // Y <- Y*P
        mm_quad_hilo(za, Ph, Pl, Zh, Zl, ra, rb, lane);        // Z <- P*Z
        __syncthreads();
        wb_hilo(Yh, Yl, ya, r, cq, lane, 1.0f, 0.0f);
        wb_hilo(Zh, Zl, za, r, cq, lane, 1.0f, 0.0f);
        __syncthreads();
    }

    const float c = 1.0f / invc;
    const float sc = sqrtf(c);
    const float isc = 1.0f / sc;
    float* yo = Ym + b * 4096;
    float* zo = Zm + b * 4096;
    for (int e = t; e < 4096; e += 256) {
        int row = e >> 6, col = e & 63;
        int idx = sw_idx(row, col);
        yo[e] = (bf16_f32((unsigned short)Yh[idx]) + bf16_f32((unsigned short)Yl[idx])) * sc;
        zo[e] = (bf16_f32((unsigned short)Zh[idx]) + bf16_f32((unsigned short)Zl[idx])) * isc;
    }
}

// ------- combine: M = Y[perm[b]] * Z[b];  A = aI + (1-a)M;  e = (1-a)(mu_s - M mu_t) -------
__global__ __launch_bounds__(256) void combine(
        const float* __restrict__ Ym, const float* __restrict__ Zm,
        const float* __restrict__ meanv,
        const int* __restrict__ perm, const float* __restrict__ alpha,
        float* __restrict__ Amat, float* __restrict__ evec) {
    const int b = blockIdx.x;
    const int t = threadIdx.x;
    const int lane = t & 63;
    const int wave = t >> 6;
    const int r = wave >> 1, cq = wave & 1;
    const int sb = perm[b];
    __shared__ __align__(16) short Yh[4096], Yl[4096], Zh[4096], Zl[4096];
    __shared__ float Mf[64 * 66];
    const float* yg = Ym + sb * 4096;
    const float* zg = Zm + b * 4096;
    for (int e = t; e < 4096; e += 256) {
        int row = e >> 6, col = e & 63;
        int idx = sw_idx(row, col);
        float y = yg[e];
        unsigned short hy = bf16_rne(y);
        Yh[idx] = (short)hy; Yl[idx] = (short)bf16_rne(y - bf16_f32(hy));
        float z = zg[e];
        unsigned short hz = bf16_rne(z);
        Zh[idx] = (short)hz; Zl[idx] = (short)bf16_rne(z - bf16_f32(hz));
    }
    __syncthreads();
    f32x16 acc;
    #pragma unroll
    for (int i = 0; i < 16; ++i) acc[i] = 0.0f;
    const int ra = 32 * r + (lane & 31);
    const int rb = 32 * cq + (lane & 31);
    mm_quad_hilo(acc, Yh, Yl, Zh, Zl, ra, rb, lane);
    const float al = alpha[b];
    float* Ab = Amat + b * 4096;
    #pragma unroll
    for (int reg = 0; reg < 16; ++reg) {
        int row = 32 * r + (reg & 3) + 8 * (reg >> 2) + 4 * (lane >> 5);
        int col = 32 * cq + (lane & 31);
        float mv = acc[reg];
        Mf[row * 66 + col] = mv;
        Ab[row * 64 + col] = (1.0f - al) * mv + ((row == col) ? al : 0.0f);
    }
    __syncthreads();
    if (t < 64) {
        const float* mt = meanv + b * 64;
        const float* ms = meanv + sb * 64;
        float s = 0.0f;
        for (int k = 0; k < 64; ++k) s += Mf[t * 66 + k] * mt[k];
        evec[b * 64 + t] = (1.0f - al) * (ms[t] - s);
    }
}

// ---------------- Pass 2: out[p] = A_b * x[p] + e_b ----------------
// __launch_bounds__(256, 8): pin VGPR <= 64 so 8 blocks/CU (32 waves/CU) are resident.
__global__ __launch_bounds__(256, 8) void pass2_apply(const float* __restrict__ x,
                                                      const float* __restrict__ Amat,
                                                      const float* __restrict__ evec,
                                                      float* __restrict__ out) {
    const int blk = blockIdx.x;
    const int b = blk / NB2;
    const int chunk = blk % NB2;
    const int t = threadIdx.x;
    const int lane = t & 63;
    const int wave = t >> 6;
    const int r = wave >> 1, q = wave & 1;
    const size_t base = (size_t)b * HW_PX * CH + (size_t)chunk * PX2 * CH;

    // A fragments for this wave's 32-row half (constant over all pixels)
    bf16x8 afrag[4];
    const float* Ab = Amat + b * 4096;
    const int arow = 32 * r + (lane & 31);
    #pragma unroll
    for (int kc = 0; kc < 4; ++kc) {
        const int k0 = kc * 16 + (lane >> 5) * 8;
        bf16x8 f;
        #pragma unroll
        for (int j = 0; j < 8; ++j)
            f[j] = (short)bf16_rne(Ab[arow * 64 + k0 + j]);
        afrag[kc] = f;
    }
    // accumulator init = e (bias), per C/D-layout row
    f32x16 einit;
    const float* eb = evec + b * 64;
    #pragma unroll
    for (int reg = 0; reg < 16; ++reg) {
        int row = 32 * r + (reg & 3) + 8 * (reg >> 2) + 4 * (lane >> 5);
        einit[reg] = eb[row];
    }

    const int px = 32 * q + (lane & 31);
    // keep the loop rolled: unrolling lifts VGPR past 64 and halves resident waves.
    #pragma unroll 1
    for (int tile = 0; tile < NT2; ++tile) {
        const size_t pbase = base + (size_t)(tile * 64 + px) * CH;
        f32x16 acc = einit;
        #pragma unroll
        for (int kc = 0; kc < 4; ++kc) {
            const int k0 = kc * 16 + (lane >> 5) * 8;
            f32x4 v0 = *(const f32x4*)&x[pbase + k0];
            f32x4 v1 = *(const f32x4*)&x[pbase + k0 + 4];
            bf16x8 bfrag;
            #pragma unroll
            for (int j = 0; j < 4; ++j) bfrag[j] = (short)bf16_rne(v0[j]);
            #pragma unroll
            for (int j = 0; j < 4; ++j) bfrag[4 + j] = (short)bf16_rne(v1[j]);
            acc = __builtin_amdgcn_mfma_f32_32x32x16_bf16(afrag[kc], bfrag, acc, 0, 0, 0);
        }
        #pragma unroll
        for (int g = 0; g < 4; ++g) {
            const int chb = 32 * r + 8 * g + 4 * (lane >> 5);
            f32x4 o = { acc[4 * g], acc[4 * g + 1], acc[4 * g + 2], acc[4 * g + 3] };
            // out is never re-read: nontemporal store keeps x resident in L2/L3.
            __builtin_nontemporal_store(o, (f32x4*)&out[pbase + chb]);
        }
    }
}

extern "C" void kernel_launch(void* const* d_in, const int* in_sizes, int n_in,
                              void* d_out, int out_size, void* d_ws, size_t ws_size,
                              hipStream_t stream) {
    (void)in_sizes; (void)n_in; (void)out_size;
    const float* x     = (const float*)d_in[0];
    const int*   perm  = (const int*)d_in[1];
    const float* alpha = (const float*)d_in[2];
    float* out = (float*)d_out;

    // pass-1 split: NB1=64 (grid 1024 -> 4 blocks/CU) if the workspace can hold the
    // larger partial buffer (17.8 MB), else fall back to the proven NB1=32 layout.
    const size_t rest_elems = (size_t)BATCH * 64 + (size_t)BATCH * 4096 * 3 + (size_t)BATCH * 64;
    const size_t need64 = ((size_t)BATCH * 64 * PARTIAL_STRIDE + rest_elems) * sizeof(float);
    const int nb1 = (ws_size >= need64) ? 64 : 32;

    float* ws      = (float*)d_ws;
    float* partial = ws;
    float* meanv   = partial + (size_t)BATCH * nb1 * PARTIAL_STRIDE;
    float* Ym      = meanv + BATCH * 64;
    float* Zm      = Ym + BATCH * 4096;
    float* Am      = Zm + BATCH * 4096;
    float* ev      = Am + BATCH * 4096;

    if (nb1 == 64) {
        pass1_cov<64><<<BATCH * 64, 256, 0, stream>>>(x, partial);
        ns_sqrt<64> <<<BATCH,      256, 0, stream>>>(partial, meanv, Ym, Zm);
    } else {
        pass1_cov<32><<<BATCH * 32, 256, 0, stream>>>(x, partial);
        ns_sqrt<32> <<<BATCH,      256, 0, stream>>>(partial, meanv, Ym, Zm);
    }
    combine    <<<BATCH,       256, 0, stream>>>(Ym, Zm, meanv, perm, alpha, Am, ev);
    pass2_apply<<<BATCH * NB2, 256, 0, stream>>>(x, Am, ev, out);
}

// Round 2
// 709.632 us; speedup vs baseline: 1.0277x; 1.0277x over previous
//
#include <hip/hip_runtime.h>

#define BATCH 16
#define CH    64
#define HW_PX 65536
#define NB2   128           // pass-2 blocks per batch: grid 2048 = exactly 8 resident blocks/CU
#define PX2   512
#define NT2   8
#define PARTIAL_STRIDE 4160 // 4096 cov partial + 64 channel sums

using bf16x8 = __attribute__((ext_vector_type(8))) short;   // 8 bf16 in 4 VGPRs
using f32x16 = __attribute__((ext_vector_type(16))) float;
using f32x4  = __attribute__((ext_vector_type(4))) float;

__device__ inline unsigned short bf16_rne(float f) {
    unsigned int u = __builtin_bit_cast(unsigned int, f);
    u += 0x7FFFu + ((u >> 16) & 1u);
    return (unsigned short)(u >> 16);
}
__device__ inline float bf16_f32(unsigned short s) {
    unsigned int u = ((unsigned int)s) << 16;
    return __builtin_bit_cast(float, u);
}
// XOR-swizzled index into a 64x64 (row,col) short array: 16B-chunk swizzle keeps
// ds_read_b128 at the 4-lane/bank floor for both row-fragment reads and staging writes.
__device__ inline int sw_idx(int row, int col) {
    return row * 64 + ((((col >> 3) ^ (row & 7)) << 3) | (col & 7));
}
__device__ inline bf16x8 ld_frag8(const short* m, int row, int o) {
    return *(const bf16x8*)&m[row * 64 + ((o ^ (row & 7)) << 3)];
}
// C += A*B for one 32x32 quadrant; A,B stored as hi/lo bf16 pairs (split-fp32).
// B is accessed via rows of B (valid because every B we pass is symmetric).
__device__ inline void mm_quad_hilo(f32x16& acc,
        const short* Ah, const short* Al,
        const short* Bh, const short* Bl,
        int ra, int rb, int lane) {
    #pragma unroll
    for (int kc = 0; kc < 4; ++kc) {
        int o = kc * 2 + (lane >> 5);
        bf16x8 ah = ld_frag8(Ah, ra, o);
        bf16x8 al = ld_frag8(Al, ra, o);
        bf16x8 bh = ld_frag8(Bh, rb, o);
        bf16x8 bl = ld_frag8(Bl, rb, o);
        acc = __builtin_amdgcn_mfma_f32_32x32x16_bf16(ah, bh, acc, 0, 0, 0);
        acc = __builtin_amdgcn_mfma_f32_32x32x16_bf16(ah, bl, acc, 0, 0, 0);
        acc = __builtin_amdgcn_mfma_f32_32x32x16_bf16(al, bh, acc, 0, 0, 0);
    }
}
// write quadrant back to LDS as hi/lo bf16: M = v*scale + diag*I
__device__ inline void wb_hilo(short* Mh, short* Ml, const f32x16& v,
                               int r, int cq, int lane, float scale, float diag) {
    #pragma unroll
    for (int reg = 0; reg < 16; ++reg) {
        int row = 32 * r + (reg & 3) + 8 * (reg >> 2) + 4 * (lane >> 5);
        int col = 32 * cq + (lane & 31);
        float f = v[reg] * scale + ((row == col) ? diag : 0.0f);
        unsigned short hi = bf16_rne(f);
        float lo = f - bf16_f32(hi);
        int idx = sw_idx(row, col);
        Mh[idx] = (short)hi;
        Ml[idx] = (short)bf16_rne(lo);
    }
}

// ---------------- Pass 1: per-batch Sum(x) and Sum(x x^T) partials ----------------
template<int NB1T>
__global__ __launch_bounds__(256) void pass1_cov(const float* __restrict__ x,
                                                 float* __restrict__ partial) {
    constexpr int PX1T = HW_PX / NB1T;   // pixels per block
    constexpr int NT1T = PX1T / 64;      // 64-pixel tiles per block
    const int blk = blockIdx.x;
    const int b = blk / NB1T;
    const int chunk = blk % NB1T;
    const size_t base = (size_t)b * HW_PX * CH + (size_t)chunk * PX1T * CH;
    const int t = threadIdx.x;
    const int lane = t & 63;
    const int wave = t >> 6;
    const int r = wave >> 1, cq = wave & 1;
    const int s_ch = t & 63;   // staging: this thread's channel
    const int s_og = t >> 6;   // staging: octet group

    __shared__ __align__(16) short xs[2][4096];  // double-buffered 64px x 64ch bf16, swizzled
    __shared__ float fsum[256];

    f32x16 acc;
    #pragma unroll
    for (int i = 0; i < 16; ++i) acc[i] = 0.0f;
    float csum = 0.0f;

    // stage tile 0
    {
        const size_t tb = base;
        #pragma unroll
        for (int p = 0; p < 2; ++p) {
            const int o = s_og + 4 * p;
            bf16x8 w;
            #pragma unroll
            for (int j = 0; j < 8; ++j) {
                float v = x[tb + (size_t)(o * 8 + j) * CH + s_ch];
                csum += v;
                w[j] = (short)bf16_rne(v);
            }
            *(bf16x8*)&xs[0][s_ch * 64 + ((o ^ (s_ch & 7)) << 3)] = w;
        }
    }
    __syncthreads();

    const int ra = 32 * r + (lane & 31);
    const int rb = 32 * cq + (lane & 31);

    for (int tile = 0; tile < NT1T; ++tile) {
        const int cur = tile & 1;
        if (tile + 1 < NT1T) {
            const size_t tb = base + (size_t)(tile + 1) * 64 * CH;
            const int nb = cur ^ 1;
            #pragma unroll
            for (int p = 0; p < 2; ++p) {
                const int o = s_og + 4 * p;
                bf16x8 w;
                #pragma unroll
                for (int j = 0; j < 8; ++j) {
                    float v = x[tb + (size_t)(o * 8 + j) * CH + s_ch];
                    csum += v;
                    w[j] = (short)bf16_rne(v);
                }
                *(bf16x8*)&xs[nb][s_ch * 64 + ((o ^ (s_ch & 7)) << 3)] = w;
            }
        }
        #pragma unroll
        for (int kc = 0; kc < 4; ++kc) {
            const int o = kc * 2 + (lane >> 5);
            bf16x8 af = *(const bf16x8*)&xs[cur][ra * 64 + ((o ^ (ra & 7)) << 3)];
            bf16x8 bg = *(const bf16x8*)&xs[cur][rb * 64 + ((o ^ (rb & 7)) << 3)];
            acc = __builtin_amdgcn_mfma_f32_32x32x16_bf16(af, bg, acc, 0, 0, 0);
        }
        __syncthreads();
    }

    float* myp = partial + (size_t)blk * PARTIAL_STRIDE;
    #pragma unroll
    for (int reg = 0; reg < 16; ++reg) {
        int row = 32 * r + (reg & 3) + 8 * (reg >> 2) + 4 * (lane >> 5);
        int col = 32 * cq + (lane & 31);
        myp[row * 64 + col] = acc[reg];
    }
    fsum[t] = csum;
    __syncthreads();
    if (t < 64) {
        myp[4096 + t] = fsum[t] + fsum[t + 64] + fsum[t + 128] + fsum[t + 192];
    }
}

// ------- Reduce partials -> cov, then coupled Newton-Schulz: Y->cov^1/2, Z->cov^-1/2 -------
template<int NB1T>
__global__ __launch_bounds__(256) void ns_sqrt(
        const float* __restrict__ partial,
        float* __restrict__ meanv,
        float* __restrict__ Ym, float* __restrict__ Zm) {
    const int b = blockIdx.x;
    const int t = threadIdx.x;
    const int lane = t & 63;
    const int wave = t >> 6;
    const int r = wave >> 1, cq = wave & 1;
    __shared__ __align__(16) short Yh[4096], Yl[4096], Zh[4096], Zl[4096], Ph[4096], Pl[4096];
    __shared__ float msh[64];
    __shared__ float csh;
    float* Cf = (float*)Ph;   // reuse P storage (16 KB) for the fp32 cov before iterations

    if (t < 64) {
        float s = 0.0f;
        for (int k = 0; k < NB1T; ++k)
            s += partial[(size_t)(b * NB1T + k) * PARTIAL_STRIDE + 4096 + t];
        float m = s / (float)HW_PX;
        msh[t] = m;
        meanv[b * 64 + t] = m;
    }
    __syncthreads();
    const float invn = 1.0f / (float)(HW_PX - 1);
    for (int e = t; e < 4096; e += 256) {
        float s = 0.0f;
        for (int k = 0; k < NB1T; ++k)
            s += partial[(size_t)(b * NB1T + k) * PARTIAL_STRIDE + e];
        int i = e >> 6, j = e & 63;
        Cf[e] = (s - (float)HW_PX * msh[i] * msh[j]) * invn;
    }
    __syncthreads();
    if (t == 0) {
        float tr = 0.0f;
        for (int i = 0; i < 64; ++i) tr += Cf[i * 64 + i];
        csh = 64.0f / tr;
    }
    __syncthreads();
    const float invc = csh;
    for (int e = t; e < 4096; e += 256) {
        int row = e >> 6, col = e & 63;
        float y = Cf[e] * invc;
        unsigned short hi = bf16_rne(y);
        float lo = y - bf16_f32(hi);
        int idx = sw_idx(row, col);
        Yh[idx] = (short)hi; Yl[idx] = (short)bf16_rne(lo);
        Zh[idx] = (row == col) ? (short)0x3F80 : (short)0;
        Zl[idx] = 0;
    }
    __syncthreads();

    const int ra = 32 * r + (lane & 31);
    const int rb = 32 * cq + (lane & 31);
    for (int it = 0; it < 5; ++it) {
        f32x16 tacc;
        #pragma unroll
        for (int i = 0; i < 16; ++i) tacc[i] = 0.0f;
        mm_quad_hilo(tacc, Zh, Zl, Yh, Yl, ra, rb, lane);      // T = Z*Y
        wb_hilo(Ph, Pl, tacc, r, cq, lane, -0.5f, 1.5f);       // P = 1.5I - 0.5T
        __syncthreads();
        f32x16 ya, za;
        #pragma unroll
        for (int i = 0; i < 16; ++i) { ya[i] = 0.0f; za[i] = 0.0f; }
        mm_quad_hilo(ya, Yh, Yl, Ph, Pl, ra, rb, lane);        // Y <- Y*P
        mm_quad_hilo(za, Ph, Pl, Zh, Zl, ra, rb, lane);        // Z <- P*Z
        __syncthreads();
        wb_hilo(Yh, Yl, ya, r, cq, lane, 1.0f, 0.0f);
        wb_hilo(Zh, Zl, za, r, cq, lane, 1.0f, 0.0f);
        __syncthreads();
    }

    const float c = 1.0f / invc;
    const float sc = sqrtf(c);
    const float isc = 1.0f / sc;
    float* yo = Ym + b * 4096;
    float* zo = Zm + b * 4096;
    for (int e = t; e < 4096; e += 256) {
        int row = e >> 6, col = e & 63;
        int idx = sw_idx(row, col);
        yo[e] = (bf16_f32((unsigned short)Yh[idx]) + bf16_f32((unsigned short)Yl[idx])) * sc;
        zo[e] = (bf16_f32((unsigned short)Zh[idx]) + bf16_f32((unsigned short)Zl[idx])) * isc;
    }
}

// ------- combine: M = Y[perm[b]] * Z[b];  A = aI + (1-a)M;  e = (1-a)(mu_s - M mu_t) -------
__global__ __launch_bounds__(256) void combine(
        const float* __restrict__ Ym, const float* __restrict__ Zm,
        const float* __restrict__ meanv,
        const int* __restrict__ perm, const float* __restrict__ alpha,
        float* __restrict__ Amat, float* __restrict__ evec) {
    const int b = blockIdx.x;
    const int t = threadIdx.x;
    const int lane = t & 63;
    const int wave = t >> 6;
    const int r = wave >> 1, cq = wave & 1;
    const int sb = perm[b];
    __shared__ __align__(16) short Yh[4096], Yl[4096], Zh[4096], Zl[4096];
    __shared__ float Mf[64 * 66];
    const float* yg = Ym + sb * 4096;
    const float* zg = Zm + b * 4096;
    for (int e = t; e < 4096; e += 256) {
        int row = e >> 6, col = e & 63;
        int idx = sw_idx(row, col);
        float y = yg[e];
        unsigned short hy = bf16_rne(y);
        Yh[idx] = (short)hy; Yl[idx] = (short)bf16_rne(y - bf16_f32(hy));
        float z = zg[e];
        unsigned short hz = bf16_rne(z);
        Zh[idx] = (short)hz; Zl[idx] = (short)bf16_rne(z - bf16_f32(hz));
    }
    __syncthreads();
    f32x16 acc;
    #pragma unroll
    for (int i = 0; i < 16; ++i) acc[i] = 0.0f;
    const int ra = 32 * r + (lane & 31);
    const int rb = 32 * cq + (lane & 31);
    mm_quad_hilo(acc, Yh, Yl, Zh, Zl, ra, rb, lane);
    const float al = alpha[b];
    float* Ab = Amat + b * 4096;
    #pragma unroll
    for (int reg = 0; reg < 16; ++reg) {
        int row = 32 * r + (reg & 3) + 8 * (reg >> 2) + 4 * (lane >> 5);
        int col = 32 * cq + (lane & 31);
        float mv = acc[reg];
        Mf[row * 66 + col] = mv;
        Ab[row * 64 + col] = (1.0f - al) * mv + ((row == col) ? al : 0.0f);
    }
    __syncthreads();
    if (t < 64) {
        const float* mt = meanv + b * 64;
        const float* ms = meanv + sb * 64;
        float s = 0.0f;
        for (int k = 0; k < 64; ++k) s += Mf[t * 66 + k] * mt[k];
        evec[b * 64 + t] = (1.0f - al) * (ms[t] - s);
    }
}

// ---------------- Pass 2: out[p] = A_b * x[p] + e_b ----------------
// __launch_bounds__(256, 8): pin VGPR <= 64 so 8 blocks/CU (32 waves/CU) are resident.
__global__ __launch_bounds__(256, 8) void pass2_apply(const float* __restrict__ x,
                                                      const float* __restrict__ Amat,
                                                      const float* __restrict__ evec,
                                                      float* __restrict__ out) {
    const int blk = blockIdx.x;
    const int b = blk / NB2;
    const int chunk = blk % NB2;
    const int t = threadIdx.x;
    const int lane = t & 63;
    const int wave = t >> 6;
    const int r = wave >> 1, q = wave & 1;
    const size_t base = (size_t)b * HW_PX * CH + (size_t)chunk * PX2 * CH;

    // A fragments for this wave's 32-row half (constant over all pixels)
    bf16x8 afrag[4];
    const float* Ab = Amat + b * 4096;
    const int arow = 32 * r + (lane & 31);
    #pragma unroll
    for (int kc = 0; kc < 4; ++kc) {
        const int k0 = kc * 16 + (lane >> 5) * 8;
        bf16x8 f;
        #pragma unroll
        for (int j = 0; j < 8; ++j)
            f[j] = (short)bf16_rne(Ab[arow * 64 + k0 + j]);
        afrag[kc] = f;
    }
    // accumulator init = e (bias), per C/D-layout row
    f32x16 einit;
    const float* eb = evec + b * 64;
    #pragma unroll
    for (int reg = 0; reg < 16; ++reg) {
        int row = 32 * r + (reg & 3) + 8 * (reg >> 2) + 4 * (lane >> 5);
        einit[reg] = eb[row];
    }

    const int px = 32 * q + (lane & 31);
    // keep the loop rolled: unrolling lifts VGPR past 64 and halves resident waves.
    #pragma unroll 1
    for (int tile = 0; tile < NT2; ++tile) {
        const size_t pbase = base + (size_t)(tile * 64 + px) * CH;
        f32x16 acc = einit;
        #pragma unroll
        for (int kc = 0; kc < 4; ++kc) {
            const int k0 = kc * 16 + (lane >> 5) * 8;
            f32x4 v0 = *(const f32x4*)&x[pbase + k0];
            f32x4 v1 = *(const f32x4*)&x[pbase + k0 + 4];
            bf16x8 bfrag;
            #pragma unroll
            for (int j = 0; j < 4; ++j) bfrag[j] = (short)bf16_rne(v0[j]);
            #pragma unroll
            for (int j = 0; j < 4; ++j) bfrag[4 + j] = (short)bf16_rne(v1[j]);
            acc = __builtin_amdgcn_mfma_f32_32x32x16_bf16(afrag[kc], bfrag, acc, 0, 0, 0);
        }
        #pragma unroll
        for (int g = 0; g < 4; ++g) {
            const int chb = 32 * r + 8 * g + 4 * (lane >> 5);
            // plain store: L2 merges the two half-line (128B) writes from the r=0/r=1
            // waves into full-line HBM writebacks (NT store broke this: WRITE 264->465MB).
            f32x4 o = { acc[4 * g], acc[4 * g + 1], acc[4 * g + 2], acc[4 * g + 3] };
            *(f32x4*)&out[pbase + chb] = o;
        }
    }
}

extern "C" void kernel_launch(void* const* d_in, const int* in_sizes, int n_in,
                              void* d_out, int out_size, void* d_ws, size_t ws_size,
                              hipStream_t stream) {
    (void)in_sizes; (void)n_in; (void)out_size;
    const float* x     = (const float*)d_in[0];
    const int*   perm  = (const int*)d_in[1];
    const float* alpha = (const float*)d_in[2];
    float* out = (float*)d_out;

    // pass-1 split: NB1=64 (grid 1024 -> 4 blocks/CU) if the workspace can hold the
    // larger partial buffer (17.8 MB), else fall back to the proven NB1=32 layout.
    const size_t rest_elems = (size_t)BATCH * 64 + (size_t)BATCH * 4096 * 3 + (size_t)BATCH * 64;
    const size_t need64 = ((size_t)BATCH * 64 * PARTIAL_STRIDE + rest_elems) * sizeof(float);
    const int nb1 = (ws_size >= need64) ? 64 : 32;

    float* ws      = (float*)d_ws;
    float* partial = ws;
    float* meanv   = partial + (size_t)BATCH * nb1 * PARTIAL_STRIDE;
    float* Ym      = meanv + BATCH * 64;
    float* Zm      = Ym + BATCH * 4096;
    float* Am      = Zm + BATCH * 4096;
    float* ev      = Am + BATCH * 4096;

    if (nb1 == 64) {
        pass1_cov<64><<<BATCH * 64, 256, 0, stream>>>(x, partial);
        ns_sqrt<64> <<<BATCH,      256, 0, stream>>>(partial, meanv, Ym, Zm);
    } else {
        pass1_cov<32><<<BATCH * 32, 256, 0, stream>>>(x, partial);
        ns_sqrt<32> <<<BATCH,      256, 0, stream>>>(partial, meanv, Ym, Zm);
    }
    combine    <<<BATCH,       256, 0, stream>>>(Ym, Zm, meanv, perm, alpha, Am, ev);
    pass2_apply<<<BATCH * NB2, 256, 0, stream>>>(x, Am, ev, out);
}

// Round 4
// 532.642 us; speedup vs baseline: 1.3692x; 1.3323x over previous
//
#include <hip/hip_runtime.h>

#define BATCH 16
#define CH    64
#define HW_PX 65536
#define NB2   64            // pass-2 blocks per batch: grid 1024 = 4 blocks/CU, all resident
#define PX2   1024          // pixels per pass-2 block
#define TPX   128           // pixels per inner tile (staged in LDS)
#define NT2   (PX2 / TPX)   // 8 tiles per block
#define PARTIAL_STRIDE 4160 // 4096 cov partial + 64 channel sums

using bf16x8 = __attribute__((ext_vector_type(8))) short;   // 8 bf16 in 4 VGPRs
using f32x16 = __attribute__((ext_vector_type(16))) float;
using f32x4  = __attribute__((ext_vector_type(4))) float;

__device__ inline unsigned short bf16_rne(float f) {
    unsigned int u = __builtin_bit_cast(unsigned int, f);
    u += 0x7FFFu + ((u >> 16) & 1u);
    return (unsigned short)(u >> 16);
}
__device__ inline float bf16_f32(unsigned short s) {
    unsigned int u = ((unsigned int)s) << 16;
    return __builtin_bit_cast(float, u);
}
// XOR-swizzled index into a [rows][64] (row,col) short array: 16B-chunk swizzle keeps
// ds_read_b128 at the 4-lane/bank floor for both row-fragment reads and staging writes.
__device__ inline int sw_idx(int row, int col) {
    return row * 64 + ((((col >> 3) ^ (row & 7)) << 3) | (col & 7));
}
__device__ inline bf16x8 ld_frag8(const short* m, int row, int o) {
    return *(const bf16x8*)&m[row * 64 + ((o ^ (row & 7)) << 3)];
}
// C += A*B for one 32x32 quadrant; A,B stored as hi/lo bf16 pairs (split-fp32).
// B is accessed via rows of B (valid because every B we pass is symmetric).
__device__ inline void mm_quad_hilo(f32x16& acc,
        const short* Ah, const short* Al,
        const short* Bh, const short* Bl,
        int ra, int rb, int lane) {
    #pragma unroll
    for (int kc = 0; kc < 4; ++kc) {
        int o = kc * 2 + (lane >> 5);
        bf16x8 ah = ld_frag8(Ah, ra, o);
        bf16x8 al = ld_frag8(Al, ra, o);
        bf16x8 bh = ld_frag8(Bh, rb, o);
        bf16x8 bl = ld_frag8(Bl, rb, o);
        acc = __builtin_amdgcn_mfma_f32_32x32x16_bf16(ah, bh, acc, 0, 0, 0);
        acc = __builtin_amdgcn_mfma_f32_32x32x16_bf16(ah, bl, acc, 0, 0, 0);
        acc = __builtin_amdgcn_mfma_f32_32x32x16_bf16(al, bh, acc, 0, 0, 0);
    }
}
// write quadrant back to LDS as hi/lo bf16: M = v*scale + diag*I
__device__ inline void wb_hilo(short* Mh, short* Ml, const f32x16& v,
                               int r, int cq, int lane, float scale, float diag) {
    #pragma unroll
    for (int reg = 0; reg < 16; ++reg) {
        int row = 32 * r + (reg & 3) + 8 * (reg >> 2) + 4 * (lane >> 5);
        int col = 32 * cq + (lane & 31);
        float f = v[reg] * scale + ((row == col) ? diag : 0.0f);
        unsigned short hi = bf16_rne(f);
        float lo = f - bf16_f32(hi);
        int idx = sw_idx(row, col);
        Mh[idx] = (short)hi;
        Ml[idx] = (short)bf16_rne(lo);
    }
}

// ---------------- Pass 1: per-batch Sum(x) and Sum(x x^T) partials ----------------
template<int NB1T>
__global__ __launch_bounds__(256) void pass1_cov(const float* __restrict__ x,
                                                 float* __restrict__ partial) {
    constexpr int PX1T = HW_PX / NB1T;   // pixels per block
    constexpr int NT1T = PX1T / 64;      // 64-pixel tiles per block
    const int blk = blockIdx.x;
    const int b = blk / NB1T;
    const int chunk = blk % NB1T;
    const size_t base = (size_t)b * HW_PX * CH + (size_t)chunk * PX1T * CH;
    const int t = threadIdx.x;
    const int lane = t & 63;
    const int wave = t >> 6;
    const int r = wave >> 1, cq = wave & 1;
    const int s_ch = t & 63;   // staging: this thread's channel
    const int s_og = t >> 6;   // staging: octet group

    __shared__ __align__(16) short xs[2][4096];  // double-buffered 64ch x 64px bf16, swizzled
    __shared__ float fsum[256];

    f32x16 acc;
    #pragma unroll
    for (int i = 0; i < 16; ++i) acc[i] = 0.0f;
    float csum = 0.0f;

    // stage tile 0
    {
        const size_t tb = base;
        #pragma unroll
        for (int p = 0; p < 2; ++p) {
            const int o = s_og + 4 * p;
            bf16x8 w;
            #pragma unroll
            for (int j = 0; j < 8; ++j) {
                float v = x[tb + (size_t)(o * 8 + j) * CH + s_ch];
                csum += v;
                w[j] = (short)bf16_rne(v);
            }
            *(bf16x8*)&xs[0][s_ch * 64 + ((o ^ (s_ch & 7)) << 3)] = w;
        }
    }
    __syncthreads();

    const int ra = 32 * r + (lane & 31);
    const int rb = 32 * cq + (lane & 31);

    for (int tile = 0; tile < NT1T; ++tile) {
        const int cur = tile & 1;
        if (tile + 1 < NT1T) {
            const size_t tb = base + (size_t)(tile + 1) * 64 * CH;
            const int nb = cur ^ 1;
            #pragma unroll
            for (int p = 0; p < 2; ++p) {
                const int o = s_og + 4 * p;
                bf16x8 w;
                #pragma unroll
                for (int j = 0; j < 8; ++j) {
                    float v = x[tb + (size_t)(o * 8 + j) * CH + s_ch];
                    csum += v;
                    w[j] = (short)bf16_rne(v);
                }
                *(bf16x8*)&xs[nb][s_ch * 64 + ((o ^ (s_ch & 7)) << 3)] = w;
            }
        }
        #pragma unroll
        for (int kc = 0; kc < 4; ++kc) {
            const int o = kc * 2 + (lane >> 5);
            bf16x8 af = *(const bf16x8*)&xs[cur][ra * 64 + ((o ^ (ra & 7)) << 3)];
            bf16x8 bg = *(const bf16x8*)&xs[cur][rb * 64 + ((o ^ (rb & 7)) << 3)];
            acc = __builtin_amdgcn_mfma_f32_32x32x16_bf16(af, bg, acc, 0, 0, 0);
        }
        __syncthreads();
    }

    float* myp = partial + (size_t)blk * PARTIAL_STRIDE;
    #pragma unroll
    for (int reg = 0; reg < 16; ++reg) {
        int row = 32 * r + (reg & 3) + 8 * (reg >> 2) + 4 * (lane >> 5);
        int col = 32 * cq + (lane & 31);
        myp[row * 64 + col] = acc[reg];
    }
    fsum[t] = csum;
    __syncthreads();
    if (t < 64) {
        myp[4096 + t] = fsum[t] + fsum[t + 64] + fsum[t + 128] + fsum[t + 192];
    }
}

// ------- Reduce partials -> cov + means, at full-chip parallelism (BATCH*8 blocks) -------
template<int NB1T>
__global__ __launch_bounds__(256) void reduce_cov(const float* __restrict__ partial,
                                                  float* __restrict__ meanv,
                                                  float* __restrict__ cov) {
    const int b = blockIdx.x >> 3;
    const int s = blockIdx.x & 7;      // 512-element slice of the 4096 cov entries
    const int t = threadIdx.x;
    __shared__ float msh[64];
    if (t < 64) {
        float su = 0.0f;
        for (int k = 0; k < NB1T; ++k)
            su += partial[(size_t)(b * NB1T + k) * PARTIAL_STRIDE + 4096 + t];
        float m = su / (float)HW_PX;
        msh[t] = m;
        if (s == 0) meanv[b * 64 + t] = m;
    }
    __syncthreads();
    const float invn = 1.0f / (float)(HW_PX - 1);
    #pragma unroll
    for (int h = 0; h < 2; ++h) {
        const int e = s * 512 + h * 256 + t;
        float su = 0.0f;
        for (int k = 0; k < NB1T; ++k)
            su += partial[(size_t)(b * NB1T + k) * PARTIAL_STRIDE + e];
        const int i = e >> 6, j = e & 63;
        cov[b * 4096 + e] = (su - (float)HW_PX * msh[i] * msh[j]) * invn;
    }
}

// ------- coupled Newton-Schulz on cov: Y->cov^1/2, Z->cov^-1/2 -------
__global__ __launch_bounds__(256) void ns_sqrt(
        const float* __restrict__ cov,
        float* __restrict__ Ym, float* __restrict__ Zm) {
    const int b = blockIdx.x;
    const int t = threadIdx.x;
    const int lane = t & 63;
    const int wave = t >> 6;
    const int r = wave >> 1, cq = wave & 1;
    __shared__ __align__(16) short Yh[4096], Yl[4096], Zh[4096], Zl[4096], Ph[4096], Pl[4096];
    __shared__ float csh;
    float* Cf = (float*)Ph;   // reuse P storage (16 KB) for the fp32 cov before iterations

    for (int e = t; e < 4096; e += 256)
        Cf[e] = cov[b * 4096 + e];
    __syncthreads();
    if (t == 0) {
        float tr = 0.0f;
        for (int i = 0; i < 64; ++i) tr += Cf[i * 64 + i];
        csh = 64.0f / tr;
    }
    __syncthreads();
    const float invc = csh;
    for (int e = t; e < 4096; e += 256) {
        int row = e >> 6, col = e & 63;
        float y = Cf[e] * invc;
        unsigned short hi = bf16_rne(y);
        float lo = y - bf16_f32(hi);
        int idx = sw_idx(row, col);
        Yh[idx] = (short)hi; Yl[idx] = (short)bf16_rne(lo);
        Zh[idx] = (row == col) ? (short)0x3F80 : (short)0;
        Zl[idx] = 0;
    }
    __syncthreads();

    const int ra = 32 * r + (lane & 31);
    const int rb = 32 * cq + (lane & 31);
    for (int it = 0; it < 5; ++it) {
        f32x16 tacc;
        #pragma unroll
        for (int i = 0; i < 16; ++i) tacc[i] = 0.0f;
        mm_quad_hilo(tacc, Zh, Zl, Yh, Yl, ra, rb, lane);      // T = Z*Y
        wb_hilo(Ph, Pl, tacc, r, cq, lane, -0.5f, 1.5f);       // P = 1.5I - 0.5T
        __syncthreads();
        f32x16 ya, za;
        #pragma unroll
        for (int i = 0; i < 16; ++i) { ya[i] = 0.0f; za[i] = 0.0f; }
        mm_quad_hilo(ya, Yh, Yl, Ph, Pl, ra, rb, lane);        // Y <- Y*P
        mm_quad_hilo(za, Ph, Pl, Zh, Zl, ra, rb, lane);        // Z <- P*Z
        __syncthreads();
        wb_hilo(Yh, Yl, ya, r, cq, lane, 1.0f, 0.0f);
        wb_hilo(Zh, Zl, za, r, cq, lane, 1.0f, 0.0f);
        __syncthreads();
    }

    const float c = 1.0f / invc;
    const float sc = sqrtf(c);
    const float isc = 1.0f / sc;
    float* yo = Ym + b * 4096;
    float* zo = Zm + b * 4096;
    for (int e = t; e < 4096; e += 256) {
        int row = e >> 6, col = e & 63;
        int idx = sw_idx(row, col);
        yo[e] = (bf16_f32((unsigned short)Yh[idx]) + bf16_f32((unsigned short)Yl[idx])) * sc;
        zo[e] = (bf16_f32((unsigned short)Zh[idx]) + bf16_f32((unsigned short)Zl[idx])) * isc;
    }
}

// ------- combine: M = Y[perm[b]] * Z[b];  A = aI + (1-a)M;  e = (1-a)(mu_s - M mu_t) -------
__global__ __launch_bounds__(256) void combine(
        const float* __restrict__ Ym, const float* __restrict__ Zm,
        const float* __restrict__ meanv,
        const int* __restrict__ perm, const float* __restrict__ alpha,
        float* __restrict__ Amat, float* __restrict__ evec) {
    const int b = blockIdx.x;
    const int t = threadIdx.x;
    const int lane = t & 63;
    const int wave = t >> 6;
    const int r = wave >> 1, cq = wave & 1;
    const int sb = perm[b];
    __shared__ __align__(16) short Yh[4096], Yl[4096], Zh[4096], Zl[4096];
    __shared__ float Mf[64 * 66];
    const float* yg = Ym + sb * 4096;
    const float* zg = Zm + b * 4096;
    for (int e = t; e < 4096; e += 256) {
        int row = e >> 6, col = e & 63;
        int idx = sw_idx(row, col);
        float y = yg[e];
        unsigned short hy = bf16_rne(y);
        Yh[idx] = (short)hy; Yl[idx] = (short)bf16_rne(y - bf16_f32(hy));
        float z = zg[e];
        unsigned short hz = bf16_rne(z);
        Zh[idx] = (short)hz; Zl[idx] = (short)bf16_rne(z - bf16_f32(hz));
    }
    __syncthreads();
    f32x16 acc;
    #pragma unroll
    for (int i = 0; i < 16; ++i) acc[i] = 0.0f;
    const int ra = 32 * r + (lane & 31);
    const int rb = 32 * cq + (lane & 31);
    mm_quad_hilo(acc, Yh, Yl, Zh, Zl, ra, rb, lane);
    const float al = alpha[b];
    float* Ab = Amat + b * 4096;
    #pragma unroll
    for (int reg = 0; reg < 16; ++reg) {
        int row = 32 * r + (reg & 3) + 8 * (reg >> 2) + 4 * (lane >> 5);
        int col = 32 * cq + (lane & 31);
        float mv = acc[reg];
        Mf[row * 66 + col] = mv;
        Ab[row * 64 + col] = (1.0f - al) * mv + ((row == col) ? al : 0.0f);
    }
    __syncthreads();
    if (t < 64) {
        const float* mt = meanv + b * 64;
        const float* ms = meanv + sb * 64;
        float s = 0.0f;
        for (int k = 0; k < 64; ++k) s += Mf[t * 66 + k] * mt[k];
        evec[b * 64 + t] = (1.0f - al) * (ms[t] - s);
    }
}

// ---------------- Pass 2 (transposed): out[px][ch] = sum_k x[px][k] * A[ch][k] + e[ch] ----
// x tile is LDS-staged with fully-coalesced f32x4 reads (lane = channel-octet of a pixel);
// MFMA uses x as the A-operand so C/D cols = channels -> stores are coalesced 128B lines.
// Each wave owns TWO 32-pixel groups (pr, pr+2) x one 32-channel half: 4 waves cover the
// full 128px x 64ch tile (round-3 bug: pr spanned only 0..1 -> half the tile unwritten).
__global__ __launch_bounds__(256, 4) void pass2_apply(const float* __restrict__ x,
                                                      const float* __restrict__ Amat,
                                                      const float* __restrict__ evec,
                                                      float* __restrict__ out) {
    const int blk = blockIdx.x;
    const int b = blk / NB2;
    const int chunk = blk % NB2;
    const int t = threadIdx.x;
    const int lane = t & 63;
    const int wave = t >> 6;
    const int pr = wave >> 1;      // pixel 32-group pair: handles pr and pr+2
    const int c2 = wave & 1;       // output-channel half (0..1)
    const size_t base = (size_t)b * HW_PX * CH + (size_t)chunk * PX2 * CH;

    __shared__ __align__(16) short xs[2][TPX * 64];   // 2 x 16 KB, swizzled [px][ch] bf16

    // B-fragments: this lane's output-channel row of A (read once; A is 16 KB, L2-hot)
    const int ch_out = 32 * c2 + (lane & 31);
    const float* Ab = Amat + b * 4096;
    bf16x8 bfrag[4];
    #pragma unroll
    for (int kc = 0; kc < 4; ++kc) {
        bf16x8 f;
        #pragma unroll
        for (int j = 0; j < 8; ++j)
            f[j] = (short)bf16_rne(Ab[ch_out * 64 + kc * 16 + (lane >> 5) * 8 + j]);
        bfrag[kc] = f;
    }
    const float ebias = evec[b * 64 + ch_out];

    // staging mapping: thread -> (pixel, channel-octet); consecutive lanes read
    // consecutive 32B chunks -> each wave covers 2 KB contiguous per p-step.
    const int oct = t & 7;
    const int spx = t >> 3;
    auto stage = [&](int buf, int tile) {
        const size_t tb = base + (size_t)tile * TPX * CH;
        #pragma unroll
        for (int p = 0; p < 4; ++p) {
            const int px = p * 32 + spx;
            const float* src = &x[tb + (size_t)px * CH + oct * 8];
            f32x4 v0 = *(const f32x4*)src;
            f32x4 v1 = *(const f32x4*)(src + 4);
            bf16x8 w;
            #pragma unroll
            for (int j = 0; j < 4; ++j) w[j] = (short)bf16_rne(v0[j]);
            #pragma unroll
            for (int j = 0; j < 4; ++j) w[4 + j] = (short)bf16_rne(v1[j]);
            *(bf16x8*)&xs[buf][px * 64 + ((oct ^ (px & 7)) << 3)] = w;
        }
    };

    stage(0, 0);
    __syncthreads();

    const int ra0 = 32 * pr + (lane & 31);        // pixel row, group pr
    const int ra1 = ra0 + 64;                     // pixel row, group pr+2
    #pragma unroll 1
    for (int tile = 0; tile < NT2; ++tile) {
        const int cur = tile & 1;
        if (tile + 1 < NT2) stage(cur ^ 1, tile + 1);

        f32x16 acc0, acc1;
        #pragma unroll
        for (int i = 0; i < 16; ++i) { acc0[i] = 0.0f; acc1[i] = 0.0f; }
        #pragma unroll
        for (int kc = 0; kc < 4; ++kc) {
            const int o = kc * 2 + (lane >> 5);
            bf16x8 ah0 = ld_frag8(&xs[cur][0], ra0, o);
            bf16x8 ah1 = ld_frag8(&xs[cur][0], ra1, o);
            acc0 = __builtin_amdgcn_mfma_f32_32x32x16_bf16(ah0, bfrag[kc], acc0, 0, 0, 0);
            acc1 = __builtin_amdgcn_mfma_f32_32x32x16_bf16(ah1, bfrag[kc], acc1, 0, 0, 0);
        }

        const size_t tb = base + (size_t)tile * TPX * CH;
        #pragma unroll
        for (int reg = 0; reg < 16; ++reg) {
            const int pxr = (reg & 3) + 8 * (reg >> 2) + 4 * (lane >> 5);
            // each half-wave writes one contiguous 128B line per reg
            out[tb + (size_t)(32 * pr + pxr) * CH + ch_out] = acc0[reg] + ebias;
            out[tb + (size_t)(32 * pr + 64 + pxr) * CH + ch_out] = acc1[reg] + ebias;
        }
        __syncthreads();
    }
}

extern "C" void kernel_launch(void* const* d_in, const int* in_sizes, int n_in,
                              void* d_out, int out_size, void* d_ws, size_t ws_size,
                              hipStream_t stream) {
    (void)in_sizes; (void)n_in; (void)out_size;
    const float* x     = (const float*)d_in[0];
    const int*   perm  = (const int*)d_in[1];
    const float* alpha = (const float*)d_in[2];
    float* out = (float*)d_out;

    // pass-1 split: NB1=64 (grid 1024 -> 4 blocks/CU) if the workspace can hold the
    // larger partial buffer; fall back to NB1=32 otherwise.
    const size_t rest_elems = (size_t)BATCH * 4096      // cov
                            + (size_t)BATCH * 64        // meanv
                            + (size_t)BATCH * 4096 * 3  // Ym, Zm, Am
                            + (size_t)BATCH * 64;       // evec
    const size_t need64 = ((size_t)BATCH * 64 * PARTIAL_STRIDE + rest_elems) * sizeof(float);
    const int nb1 = (ws_size >= need64) ? 64 : 32;

    float* ws      = (float*)d_ws;
    float* partial = ws;
    float* cov     = partial + (size_t)BATCH * nb1 * PARTIAL_STRIDE;
    float* meanv   = cov + BATCH * 4096;
    float* Ym      = meanv + BATCH * 64;
    float* Zm      = Ym + BATCH * 4096;
    float* Am      = Zm + BATCH * 4096;
    float* ev      = Am + BATCH * 4096;

    if (nb1 == 64) {
        pass1_cov<64> <<<BATCH * 64, 256, 0, stream>>>(x, partial);
        reduce_cov<64><<<BATCH * 8,  256, 0, stream>>>(partial, meanv, cov);
    } else {
        pass1_cov<32> <<<BATCH * 32, 256, 0, stream>>>(x, partial);
        reduce_cov<32><<<BATCH * 8,  256, 0, stream>>>(partial, meanv, cov);
    }
    ns_sqrt    <<<BATCH,       256, 0, stream>>>(cov, Ym, Zm);
    combine    <<<BATCH,       256, 0, stream>>>(Ym, Zm, meanv, perm, alpha, Am, ev);
    pass2_apply<<<BATCH * NB2, 256, 0, stream>>>(x, Am, ev, out);
}